// Round 9
// baseline (282.325 us; speedup 1.0000x reference)
//
#include <hip/hip_runtime.h>
#include <math.h>

#define DIM 1024
#define T_SEQ 2048
#define NBATCH 2
#define HEADS 16
#define HD 64
#define NTOK 4096  // NBATCH * T_SEQ
#define THRESH 0.29514f
#define SHARP 15.0f
#define LOG2E 1.4426950408889634f

typedef __attribute__((ext_vector_type(8))) short bf16x8;
typedef __attribute__((ext_vector_type(4))) float f32x4;
typedef __attribute__((ext_vector_type(4))) unsigned int u32x4;

__device__ __forceinline__ unsigned short f2b(float f) {
    unsigned int u = __float_as_uint(f);
    unsigned int r = (u + 0x7FFFu + ((u >> 16) & 1u)) >> 16;
    return (unsigned short)r;
}
__device__ __forceinline__ float b2f(unsigned short u) {
    return __uint_as_float(((unsigned int)u) << 16);
}
// pack two f32 -> bf16x2 dword (lo in low half), round-half-up (<=0.5 ulp).
__device__ __forceinline__ unsigned int pack2_bf16(float lo, float hi) {
    unsigned int a = __float_as_uint(lo) + 0x8000u;
    unsigned int b = __float_as_uint(hi) + 0x8000u;
    return __builtin_amdgcn_perm(b, a, 0x07060302u);  // {b.b3,b.b2,a.b3,a.b2}
}

__device__ __forceinline__ void async_cp16(const unsigned short* g, unsigned short* l) {
    __builtin_amdgcn_global_load_lds(
        (const __attribute__((address_space(1))) unsigned int*)g,
        (__attribute__((address_space(3))) unsigned int*)l, 16, 0, 0);
}

// ---------------------------------------------------------------------------
// Kernel 1: fused LayerNorm -> bf16 x_norm, plus bf16 cast of raw x.
// ---------------------------------------------------------------------------
__global__ __launch_bounds__(256) void ln_xnorm_kernel(
    const float* __restrict__ x, const float* __restrict__ lnw, const float* __restrict__ lnb,
    unsigned short* __restrict__ xnb, unsigned short* __restrict__ xb) {
    int row = blockIdx.x * 4 + (threadIdx.x >> 6);
    int lane = threadIdx.x & 63;
    const float4* xr = (const float4*)(x + (size_t)row * DIM);
    float4 v[4];
    float s = 0.f, ss = 0.f;
#pragma unroll
    for (int i = 0; i < 4; i++) {
        v[i] = xr[lane + i * 64];
        s += v[i].x + v[i].y + v[i].z + v[i].w;
        ss += v[i].x * v[i].x + v[i].y * v[i].y + v[i].z * v[i].z + v[i].w * v[i].w;
    }
#pragma unroll
    for (int off = 32; off; off >>= 1) {
        s += __shfl_xor(s, off);
        ss += __shfl_xor(ss, off);
    }
    float m = s * (1.f / DIM);
    float rstd = rsqrtf(ss * (1.f / DIM) - m * m + 1e-5f);
#pragma unroll
    for (int i = 0; i < 4; i++) {
        int e = (lane + i * 64) * 4;
        float4 lw = *(const float4*)&lnw[e];
        float4 lb = *(const float4*)&lnb[e];
        ushort4 un, ur;
        un.x = f2b((v[i].x - m) * rstd * lw.x + lb.x);
        un.y = f2b((v[i].y - m) * rstd * lw.y + lb.y);
        un.z = f2b((v[i].z - m) * rstd * lw.z + lb.z);
        un.w = f2b((v[i].w - m) * rstd * lw.w + lb.w);
        ur.x = f2b(v[i].x); ur.y = f2b(v[i].y); ur.z = f2b(v[i].z); ur.w = f2b(v[i].w);
        *(ushort4*)&xnb[(size_t)row * DIM + e] = un;
        *(ushort4*)&xb[(size_t)row * DIM + e] = ur;
    }
}

// ---------------------------------------------------------------------------
// Kernel 2: fp32 [K][N] weight -> bf16 transposed [N][K], via fp32 LDS tile.
// ---------------------------------------------------------------------------
__global__ __launch_bounds__(256) void wtrans_kernel(
    const float* __restrict__ W0, const float* __restrict__ W1,
    const float* __restrict__ W2, const float* __restrict__ W3,
    unsigned short* __restrict__ T0, unsigned short* __restrict__ T1,
    unsigned short* __restrict__ T2, unsigned short* __restrict__ T3) {
    __shared__ float tile[64][65];
    const int z = blockIdx.z;
    const float* W = (z == 0) ? W0 : (z == 1) ? W1 : (z == 2) ? W2 : W3;
    unsigned short* T = (z == 0) ? T0 : (z == 1) ? T1 : (z == 2) ? T2 : T3;
    const int k0 = blockIdx.x * 64, n0 = blockIdx.y * 64;
    const int r = threadIdx.x >> 3;
    const int c = (threadIdx.x & 7) * 8;
#pragma unroll
    for (int half = 0; half < 2; half++) {
        int rr = r + half * 32;
        float4 a = *(const float4*)&W[(size_t)(k0 + rr) * DIM + n0 + c];
        float4 b = *(const float4*)&W[(size_t)(k0 + rr) * DIM + n0 + c + 4];
        tile[rr][c + 0] = a.x; tile[rr][c + 1] = a.y; tile[rr][c + 2] = a.z; tile[rr][c + 3] = a.w;
        tile[rr][c + 4] = b.x; tile[rr][c + 5] = b.y; tile[rr][c + 6] = b.z; tile[rr][c + 7] = b.w;
    }
    __syncthreads();
#pragma unroll
    for (int half = 0; half < 2; half++) {
        int dd = r + half * 32;
        bf16x8 o;
#pragma unroll
        for (int j = 0; j < 8; j++) o[j] = (short)f2b(tile[c + j][dd]);
        *(bf16x8*)&T[(size_t)(n0 + dd) * DIM + k0 + c] = o;
    }
}

// ---------------------------------------------------------------------------
// Kernel 3: bf16 MFMA GEMM, 128x128 tile, BK=32, 4 waves (2x2).
// MODE 0: z=0/1 (Q/K): fused l2norm + gate in epilogue; z=2 (V): plain bf16.
// MODE 1: C = collb @ Wot^T + bias, fp32 out [B,T,D].
// ---------------------------------------------------------------------------
template <int MODE>
__global__ __launch_bounds__(256) void gemm_mfma_kernel(
    const unsigned short* __restrict__ A0, const unsigned short* __restrict__ A2,
    const unsigned short* __restrict__ Bt0, const unsigned short* __restrict__ Bt1,
    const unsigned short* __restrict__ Bt2, const float* __restrict__ bias,
    const float* __restrict__ gq, const float* __restrict__ gk,
    unsigned short* __restrict__ Oq, unsigned short* __restrict__ Ok,
    unsigned short* __restrict__ Ov, float* __restrict__ gq_t, float* __restrict__ gk_t,
    float* __restrict__ Oout) {
    __shared__ __align__(16) unsigned short As[128 * 32];
    __shared__ __align__(16) unsigned short Bs[128 * 32];
    const int tid = threadIdx.x;
    const int lane = tid & 63, w = tid >> 6;
    const int l16 = lane & 15, quad = lane >> 4;
    const int wm = w >> 1, wn = w & 1;
    const int m0 = blockIdx.x * 128, n0 = blockIdx.y * 128;
    const unsigned short* A;
    const unsigned short* Bt;
    int z = 0;
    if constexpr (MODE == 0) {
        z = blockIdx.z;
        A = (z == 2) ? A2 : A0;
        Bt = (z == 0) ? Bt0 : (z == 1) ? Bt1 : Bt2;
    } else {
        A = A0;
        Bt = Bt0;
    }
    f32x4 acc[4][4] = {};
    const int kswz = (l16 >> 1) & 3;

    for (int k0 = 0; k0 < DIM; k0 += 32) {
        __syncthreads();
#pragma unroll
        for (int i = 0; i < 2; i++) {
            int linear = i * 256 + tid;
            int m = linear >> 2, kgp = linear & 3;
            int kgl = kgp ^ ((m >> 1) & 3);
            async_cp16(A + (size_t)(m0 + m) * DIM + k0 + kgl * 8, As + linear * 8);
            async_cp16(Bt + (size_t)(n0 + m) * DIM + k0 + kgl * 8, Bs + linear * 8);
        }
        __syncthreads();
        bf16x8 af[4], bfr[4];
#pragma unroll
        for (int t = 0; t < 4; t++) {
            int ma = wm * 64 + t * 16 + l16;
            af[t] = *(const bf16x8*)(As + ma * 32 + ((quad ^ kswz) * 8));
            int nb = wn * 64 + t * 16 + l16;
            bfr[t] = *(const bf16x8*)(Bs + nb * 32 + ((quad ^ kswz) * 8));
        }
#pragma unroll
        for (int mt = 0; mt < 4; mt++)
#pragma unroll
            for (int nt = 0; nt < 4; nt++)
                acc[mt][nt] =
                    __builtin_amdgcn_mfma_f32_16x16x32_bf16(af[mt], bfr[nt], acc[mt][nt], 0, 0, 0);
    }

    if constexpr (MODE == 0) {
        const int h = (n0 + wn * 64) >> 6;  // this wave's head
        if (z <= 1) {
            const float* gvec = (z == 0) ? gq : gk;
            float* gate = (z == 0) ? gq_t : gk_t;
            unsigned short* O = (z == 0) ? Oq : Ok;
            float gv[4];
#pragma unroll
            for (int nt = 0; nt < 4; nt++) gv[nt] = gvec[nt * 16 + l16];
#pragma unroll
            for (int mt = 0; mt < 4; mt++) {
#pragma unroll
                for (int r = 0; r < 4; r++) {
                    float ss = 0.f;
#pragma unroll
                    for (int nt = 0; nt < 4; nt++) ss += acc[mt][nt][r] * acc[mt][nt][r];
#pragma unroll
                    for (int msk = 1; msk < 16; msk <<= 1) ss += __shfl_xor(ss, msk);
                    float rn = __builtin_amdgcn_rcpf(fmaxf(sqrtf(ss), 1e-12f));
                    float vn[4], gg = 0.f;
#pragma unroll
                    for (int nt = 0; nt < 4; nt++) {
                        vn[nt] = acc[mt][nt][r] * rn;
                        gg += vn[nt] * gv[nt];
                    }
#pragma unroll
                    for (int msk = 1; msk < 16; msk <<= 1) gg += __shfl_xor(gg, msk);
                    int tok = m0 + wm * 64 + mt * 16 + quad * 4 + r;
                    int b = tok >> 11, t = tok & 2047;
                    size_t rowbase = ((size_t)(b * HEADS + h) * T_SEQ + t) * HD;
#pragma unroll
                    for (int nt = 0; nt < 4; nt++) O[rowbase + nt * 16 + l16] = f2b(vn[nt]);
                    if (l16 == 0) gate[(b * HEADS + h) * T_SEQ + t] = gg;
                }
            }
        } else {
#pragma unroll
            for (int mt = 0; mt < 4; mt++) {
#pragma unroll
                for (int r = 0; r < 4; r++) {
                    int tok = m0 + wm * 64 + mt * 16 + quad * 4 + r;
                    int b = tok >> 11, t = tok & 2047;
                    size_t rowbase = ((size_t)(b * HEADS + h) * T_SEQ + t) * HD;
#pragma unroll
                    for (int nt = 0; nt < 4; nt++)
                        Ov[rowbase + nt * 16 + l16] = f2b(acc[mt][nt][r]);
                }
            }
        }
    } else {
        float bias_r[4];
#pragma unroll
        for (int nt = 0; nt < 4; nt++) bias_r[nt] = bias[n0 + wn * 64 + nt * 16 + l16];
#pragma unroll
        for (int mt = 0; mt < 4; mt++) {
#pragma unroll
            for (int r = 0; r < 4; r++) {
                int tok = m0 + wm * 64 + mt * 16 + quad * 4 + r;
#pragma unroll
                for (int nt = 0; nt < 4; nt++) {
                    int n = n0 + wn * 64 + nt * 16 + l16;
                    Oout[(size_t)tok * DIM + n] = acc[mt][nt][r] + bias_r[nt];
                }
            }
        }
    }
}

// ---------------------------------------------------------------------------
// Kernel 4: bf16 transpose V[bh][t][d] -> Vt[bh][d][t], fused gate_k scale.
// ---------------------------------------------------------------------------
__global__ __launch_bounds__(256) void vtrans_kernel(const unsigned short* __restrict__ Vn,
                                                     const float* __restrict__ gk_t,
                                                     unsigned short* __restrict__ Vt) {
    __shared__ float tile[64][65];
    const int bh = blockIdx.y;
    const int t0 = blockIdx.x * 64;
    const int r = threadIdx.x >> 3;
    const int c = (threadIdx.x & 7) * 8;
    const unsigned short* src = Vn + (size_t)bh * T_SEQ * HD;
#pragma unroll
    for (int half = 0; half < 2; half++) {
        int rr = r + half * 32;
        float gkv = gk_t[bh * T_SEQ + t0 + rr];
        bf16x8 v = *(const bf16x8*)(src + (size_t)(t0 + rr) * HD + c);
#pragma unroll
        for (int j = 0; j < 8; j++) tile[rr][c + j] = b2f((unsigned short)v[j]) * gkv;
    }
    __syncthreads();
    unsigned short* dst = Vt + (size_t)bh * HD * T_SEQ;
#pragma unroll
    for (int half = 0; half < 2; half++) {
        int dd = r + half * 32;
        bf16x8 o;
#pragma unroll
        for (int j = 0; j < 8; j++) o[j] = (short)f2b(tile[c + j][dd]);
        *(bf16x8*)(dst + (size_t)dd * T_SEQ + t0 + c) = o;
    }
}

// ---------------------------------------------------------------------------
// Kernel 5: MFMA gated attention — NO LDS, no barriers. Fragments loaded
// directly global->VGPR (the fragment access pattern is 64B-segment
// coalesced for both K and V^T; K/V^T re-reads are served by L1/L2).
// Waves are fully independent -> VALU and MFMA phases of different waves
// interleave freely. fk double-buffered across chunks; fv loaded at chunk
// top (~600 cyc of QK+sigmoid before first use hides L2 latency).
// QK^T computed transposed (S^T = K Q^T); SV B-operand built in-register
// via v_permlane16_swap_b32; induced k-slot permutation compensated by
// sigma-permuted fv s-offsets. gate_k pre-folded into V; gate_q epilogue.
// ---------------------------------------------------------------------------
__global__ __launch_bounds__(256) void attn_mfma_kernel(
    const unsigned short* __restrict__ Qn, const unsigned short* __restrict__ Kn,
    const unsigned short* __restrict__ Vt, const float* __restrict__ gateq,
    unsigned short* __restrict__ collb) {
    const int tid = threadIdx.x;
    const int lane = tid & 63, w = tid >> 6;
    const int quad = lane >> 4, l16 = lane & 15;
    const int t0 = blockIdx.x * 128;
    const int h = blockIdx.y, b = blockIdx.z;
    const int bh = b * HEADS + h;
    const size_t base = (size_t)bh * T_SEQ * HD;  // == bh*HD*T_SEQ for Vt
    constexpr float K1 = -SHARP * LOG2E;
    constexpr float K0 = THRESH * SHARP * LOG2E;

    // Detect v_permlane16_swap_b32 output order once (uniform).
    int det0 = quad, det1 = quad + 4;
    asm("v_permlane16_swap_b32 %0, %1" : "+v"(det0), "+v"(det1));
    const bool flagA = (__builtin_amdgcn_readfirstlane(det0) == 0);

    // Q (B-operand of QK) fragments: 32 rows/wave, 2 m-tiles, in regs.
    bf16x8 fq[2][2];
#pragma unroll
    for (int mt = 0; mt < 2; mt++) {
        const unsigned short* qrow = Qn + base + (size_t)(t0 + w * 32 + mt * 16 + l16) * HD;
        fq[mt][0] = *(const bf16x8*)(qrow + quad * 8);
        fq[mt][1] = *(const bf16x8*)(qrow + 32 + quad * 8);
    }

    f32x4 oacc[4][2] = {};  // [dt][mt], O^T C-layout

    // K fragment rows for this lane: row = s0 + ct*16 + l16, two 16B groups.
    const unsigned short* kbase = Kn + base + (size_t)l16 * HD + quad * 8;
    // V^T fragment rows: row d = dt*16+l16, col = s0 + sigma(quad)*8 (+32*kh)
    const int sig = 2 * (quad & 1) + (quad >> 1);  // {0,2,1,3}
    const unsigned short* vbase = Vt + base + (size_t)l16 * T_SEQ + sig * 8;

    auto load_fk = [&](int s0, bf16x8* fk) {
#pragma unroll
        for (int ct = 0; ct < 4; ct++) {
            const unsigned short* kr = kbase + (size_t)(s0 + ct * 16) * HD;
            fk[2 * ct] = *(const bf16x8*)(kr);
            fk[2 * ct + 1] = *(const bf16x8*)(kr + 32);
        }
    };
    auto load_fv = [&](int s0, bf16x8* fv) {
#pragma unroll
        for (int kh = 0; kh < 2; kh++)
#pragma unroll
            for (int dt = 0; dt < 4; dt++)
                fv[kh * 4 + dt] = *(const bf16x8*)(vbase + (size_t)(dt * 16) * T_SEQ + s0 + kh * 32);
    };

    auto compute = [&](const bf16x8* fk, const bf16x8* fv) {
        // ---- QK phase: S^T = K Q^T; sigmoid; bf16 S stays in registers ----
        unsigned int p[2][4][2];  // [mt][ct][dword]; lane: s=ct*16+quad*4+r, m=mt*16+l16
#pragma unroll
        for (int ct = 0; ct < 4; ct++) {
#pragma unroll
            for (int mt = 0; mt < 2; mt++) {
                f32x4 sacc = {0.f, 0.f, 0.f, 0.f};
                sacc = __builtin_amdgcn_mfma_f32_16x16x32_bf16(fk[2 * ct], fq[mt][0], sacc, 0, 0, 0);
                sacc = __builtin_amdgcn_mfma_f32_16x16x32_bf16(fk[2 * ct + 1], fq[mt][1], sacc, 0, 0, 0);
                float w0 = __builtin_amdgcn_rcpf(1.f + __builtin_amdgcn_exp2f(fmaf(sacc[0], K1, K0)));
                float w1 = __builtin_amdgcn_rcpf(1.f + __builtin_amdgcn_exp2f(fmaf(sacc[1], K1, K0)));
                float w2 = __builtin_amdgcn_rcpf(1.f + __builtin_amdgcn_exp2f(fmaf(sacc[2], K1, K0)));
                float w3 = __builtin_amdgcn_rcpf(1.f + __builtin_amdgcn_exp2f(fmaf(sacc[3], K1, K0)));
                p[mt][ct][0] = pack2_bf16(w0, w1);
                p[mt][ct][1] = pack2_bf16(w2, w3);
            }
        }
        // ---- SV phase: O^T += V^T S^T, B-frag built via permlane16_swap ----
#pragma unroll
        for (int kh = 0; kh < 2; kh++) {
#pragma unroll
            for (int mt = 0; mt < 2; mt++) {
                unsigned int aL = p[mt][2 * kh][0], aH = p[mt][2 * kh][1];
                unsigned int bL = p[mt][2 * kh + 1][0], bH = p[mt][2 * kh + 1][1];
                asm("v_permlane16_swap_b32 %0, %1" : "+v"(aL), "+v"(bL));
                asm("v_permlane16_swap_b32 %0, %1" : "+v"(aH), "+v"(bH));
                u32x4 bt;
                bt.x = flagA ? aL : bL;
                bt.y = flagA ? aH : bH;
                bt.z = flagA ? bL : aL;
                bt.w = flagA ? bH : aH;
                bf16x8 fs = __builtin_bit_cast(bf16x8, bt);
#pragma unroll
                for (int dt = 0; dt < 4; dt++)
                    oacc[dt][mt] = __builtin_amdgcn_mfma_f32_16x16x32_bf16(
                        fv[kh * 4 + dt], fs, oacc[dt][mt], 0, 0, 0);
            }
        }
    };

    bf16x8 fkA[8], fkB[8], fvC[8];
    load_fk(0, fkA);
    for (int i = 0; i < T_SEQ / 64; i += 2) {
        load_fv(i * 64, fvC);            // this chunk's V (used after sigmoid)
        load_fk(i * 64 + 64, fkB);       // next chunk's K
        compute(fkA, fvC);
        load_fv(i * 64 + 64, fvC);
        if (i + 2 < T_SEQ / 64) load_fk(i * 64 + 128, fkA);
        compute(fkB, fvC);
    }

    // ---- epilogue: O^T lanes hold 4 consecutive d; * gate_q, b64 writes ----
#pragma unroll
    for (int mt = 0; mt < 2; mt++) {
        int t = t0 + w * 32 + mt * 16 + l16;
        float gq_v = gateq[bh * T_SEQ + t];
        unsigned short* dst = collb + ((size_t)b * T_SEQ + t) * DIM + h * HD;
#pragma unroll
        for (int dt = 0; dt < 4; dt++) {
            ushort4 o;
            o.x = f2b(oacc[dt][mt][0] * gq_v);
            o.y = f2b(oacc[dt][mt][1] * gq_v);
            o.z = f2b(oacc[dt][mt][2] * gq_v);
            o.w = f2b(oacc[dt][mt][3] * gq_v);
            *(ushort4*)(dst + dt * 16 + quad * 4) = o;
        }
    }
}

// ---------------------------------------------------------------------------
extern "C" void kernel_launch(void* const* d_in, const int* in_sizes, int n_in,
                              void* d_out, int out_size, void* d_ws, size_t ws_size,
                              hipStream_t stream) {
    const float* x = (const float*)d_in[0];
    const float* Wq = (const float*)d_in[1];
    const float* Wk = (const float*)d_in[2];
    const float* Wv = (const float*)d_in[3];
    const float* gq = (const float*)d_in[4];
    const float* gk = (const float*)d_in[5];
    const float* Wo = (const float*)d_in[6];
    const float* bo = (const float*)d_in[7];
    const float* lnw = (const float*)d_in[8];
    const float* lnb = (const float*)d_in[9];
    float* out = (float*)d_out;

    // Workspace ~51 MB. Aliases safe by stream ordering: Vt overwrites xnb
    // (dead after QKV GEMM); collb overwrites xb (dead after QKV GEMM).
    unsigned short* ws = (unsigned short*)d_ws;
    unsigned short* xnb = ws;                           // bf16 [4096][1024]
    unsigned short* xb = xnb + (size_t)NTOK * DIM;      // bf16 [4096][1024]
    unsigned short* Wqt = xb + (size_t)NTOK * DIM;      // bf16 [1024][1024] (W^T)
    unsigned short* Wkt = Wqt + (size_t)DIM * DIM;
    unsigned short* Wvt = Wkt + (size_t)DIM * DIM;
    unsigned short* Wot = Wvt + (size_t)DIM * DIM;
    unsigned short* Q16 = Wot + (size_t)DIM * DIM;      // bf16 [B,H,T,hd] (normalized)
    unsigned short* K16 = Q16 + (size_t)NTOK * DIM;     // bf16 (normalized)
    unsigned short* Vn = K16 + (size_t)NTOK * DIM;      // bf16 [B,H,T,hd]
    float* gq_t = (float*)(Vn + (size_t)NTOK * DIM);    // [B,H,T]
    float* gk_t = gq_t + NBATCH * HEADS * T_SEQ;
    unsigned short* Vt = xnb;    // alias: bf16 [B,H,hd,T], gk-scaled
    unsigned short* collb = xb;  // alias

    ln_xnorm_kernel<<<NTOK / 4, 256, 0, stream>>>(x, lnw, lnb, xnb, xb);
    wtrans_kernel<<<dim3(16, 16, 4), 256, 0, stream>>>(Wq, Wk, Wv, Wo, Wqt, Wkt, Wvt, Wot);
    gemm_mfma_kernel<0><<<dim3(NTOK / 128, DIM / 128, 3), 256, 0, stream>>>(
        xnb, xb, Wqt, Wkt, Wvt, nullptr, gq, gk, Q16, K16, Vn, gq_t, gk_t, nullptr);
    vtrans_kernel<<<dim3(T_SEQ / 64, NBATCH * HEADS), 256, 0, stream>>>(Vn, gk_t, Vt);
    attn_mfma_kernel<<<dim3(T_SEQ / 128, HEADS, NBATCH), 256, 0, stream>>>(
        Q16, K16, Vt, gq_t, collb);
    gemm_mfma_kernel<1><<<dim3(NTOK / 128, DIM / 128, 1), 256, 0, stream>>>(
        collb, nullptr, Wot, nullptr, nullptr, bo, nullptr, nullptr, nullptr, nullptr, nullptr,
        nullptr, nullptr, out);
}

// Round 10
// 229.266 us; speedup vs baseline: 1.2314x; 1.2314x over previous
//
#include <hip/hip_runtime.h>
#include <math.h>

#define DIM 1024
#define T_SEQ 2048
#define NBATCH 2
#define HEADS 16
#define HD 64
#define NTOK 4096  // NBATCH * T_SEQ
#define THRESH 0.29514f
#define SHARP 15.0f
#define LOG2E 1.4426950408889634f

typedef __attribute__((ext_vector_type(8))) short bf16x8;
typedef __attribute__((ext_vector_type(4))) float f32x4;
typedef __attribute__((ext_vector_type(4))) unsigned int u32x4;

__device__ __forceinline__ unsigned short f2b(float f) {
    unsigned int u = __float_as_uint(f);
    unsigned int r = (u + 0x7FFFu + ((u >> 16) & 1u)) >> 16;
    return (unsigned short)r;
}
__device__ __forceinline__ float b2f(unsigned short u) {
    return __uint_as_float(((unsigned int)u) << 16);
}
// pack two f32 -> bf16x2 dword (lo in low half), round-half-up (<=0.5 ulp).
__device__ __forceinline__ unsigned int pack2_bf16(float lo, float hi) {
    unsigned int a = __float_as_uint(lo) + 0x8000u;
    unsigned int b = __float_as_uint(hi) + 0x8000u;
    return __builtin_amdgcn_perm(b, a, 0x07060302u);  // {b.b3,b.b2,a.b3,a.b2}
}

__device__ __forceinline__ void async_cp16(const unsigned short* g, unsigned short* l) {
    __builtin_amdgcn_global_load_lds(
        (const __attribute__((address_space(1))) unsigned int*)g,
        (__attribute__((address_space(3))) unsigned int*)l, 16, 0, 0);
}

// ---------------------------------------------------------------------------
// Kernel 1: fused LayerNorm -> bf16 x_norm, plus bf16 cast of raw x.
// ---------------------------------------------------------------------------
__global__ __launch_bounds__(256) void ln_xnorm_kernel(
    const float* __restrict__ x, const float* __restrict__ lnw, const float* __restrict__ lnb,
    unsigned short* __restrict__ xnb, unsigned short* __restrict__ xb) {
    int row = blockIdx.x * 4 + (threadIdx.x >> 6);
    int lane = threadIdx.x & 63;
    const float4* xr = (const float4*)(x + (size_t)row * DIM);
    float4 v[4];
    float s = 0.f, ss = 0.f;
#pragma unroll
    for (int i = 0; i < 4; i++) {
        v[i] = xr[lane + i * 64];
        s += v[i].x + v[i].y + v[i].z + v[i].w;
        ss += v[i].x * v[i].x + v[i].y * v[i].y + v[i].z * v[i].z + v[i].w * v[i].w;
    }
#pragma unroll
    for (int off = 32; off; off >>= 1) {
        s += __shfl_xor(s, off);
        ss += __shfl_xor(ss, off);
    }
    float m = s * (1.f / DIM);
    float rstd = rsqrtf(ss * (1.f / DIM) - m * m + 1e-5f);
#pragma unroll
    for (int i = 0; i < 4; i++) {
        int e = (lane + i * 64) * 4;
        float4 lw = *(const float4*)&lnw[e];
        float4 lb = *(const float4*)&lnb[e];
        ushort4 un, ur;
        un.x = f2b((v[i].x - m) * rstd * lw.x + lb.x);
        un.y = f2b((v[i].y - m) * rstd * lw.y + lb.y);
        un.z = f2b((v[i].z - m) * rstd * lw.z + lb.z);
        un.w = f2b((v[i].w - m) * rstd * lw.w + lb.w);
        ur.x = f2b(v[i].x); ur.y = f2b(v[i].y); ur.z = f2b(v[i].z); ur.w = f2b(v[i].w);
        *(ushort4*)&xnb[(size_t)row * DIM + e] = un;
        *(ushort4*)&xb[(size_t)row * DIM + e] = ur;
    }
}

// ---------------------------------------------------------------------------
// Kernel 2: fp32 [K][N] weight -> bf16 transposed [N][K], via fp32 LDS tile.
// ---------------------------------------------------------------------------
__global__ __launch_bounds__(256) void wtrans_kernel(
    const float* __restrict__ W0, const float* __restrict__ W1,
    const float* __restrict__ W2, const float* __restrict__ W3,
    unsigned short* __restrict__ T0, unsigned short* __restrict__ T1,
    unsigned short* __restrict__ T2, unsigned short* __restrict__ T3) {
    __shared__ float tile[64][65];
    const int z = blockIdx.z;
    const float* W = (z == 0) ? W0 : (z == 1) ? W1 : (z == 2) ? W2 : W3;
    unsigned short* T = (z == 0) ? T0 : (z == 1) ? T1 : (z == 2) ? T2 : T3;
    const int k0 = blockIdx.x * 64, n0 = blockIdx.y * 64;
    const int r = threadIdx.x >> 3;
    const int c = (threadIdx.x & 7) * 8;
#pragma unroll
    for (int half = 0; half < 2; half++) {
        int rr = r + half * 32;
        float4 a = *(const float4*)&W[(size_t)(k0 + rr) * DIM + n0 + c];
        float4 b = *(const float4*)&W[(size_t)(k0 + rr) * DIM + n0 + c + 4];
        tile[rr][c + 0] = a.x; tile[rr][c + 1] = a.y; tile[rr][c + 2] = a.z; tile[rr][c + 3] = a.w;
        tile[rr][c + 4] = b.x; tile[rr][c + 5] = b.y; tile[rr][c + 6] = b.z; tile[rr][c + 7] = b.w;
    }
    __syncthreads();
#pragma unroll
    for (int half = 0; half < 2; half++) {
        int dd = r + half * 32;
        bf16x8 o;
#pragma unroll
        for (int j = 0; j < 8; j++) o[j] = (short)f2b(tile[c + j][dd]);
        *(bf16x8*)&T[(size_t)(n0 + dd) * DIM + k0 + c] = o;
    }
}

// ---------------------------------------------------------------------------
// Kernel 3: bf16 MFMA GEMM, 128x128 tile, BK=32, 4 waves (2x2).
// MODE 0: z=0/1 (Q/K): fused l2norm + gate in epilogue; z=2 (V): plain bf16.
// MODE 1: C = collb @ Wot^T + bias, fp32 out [B,T,D].
// ---------------------------------------------------------------------------
template <int MODE>
__global__ __launch_bounds__(256) void gemm_mfma_kernel(
    const unsigned short* __restrict__ A0, const unsigned short* __restrict__ A2,
    const unsigned short* __restrict__ Bt0, const unsigned short* __restrict__ Bt1,
    const unsigned short* __restrict__ Bt2, const float* __restrict__ bias,
    const float* __restrict__ gq, const float* __restrict__ gk,
    unsigned short* __restrict__ Oq, unsigned short* __restrict__ Ok,
    unsigned short* __restrict__ Ov, float* __restrict__ gq_t, float* __restrict__ gk_t,
    float* __restrict__ Oout) {
    __shared__ __align__(16) unsigned short As[128 * 32];
    __shared__ __align__(16) unsigned short Bs[128 * 32];
    const int tid = threadIdx.x;
    const int lane = tid & 63, w = tid >> 6;
    const int l16 = lane & 15, quad = lane >> 4;
    const int wm = w >> 1, wn = w & 1;
    const int m0 = blockIdx.x * 128, n0 = blockIdx.y * 128;
    const unsigned short* A;
    const unsigned short* Bt;
    int z = 0;
    if constexpr (MODE == 0) {
        z = blockIdx.z;
        A = (z == 2) ? A2 : A0;
        Bt = (z == 0) ? Bt0 : (z == 1) ? Bt1 : Bt2;
    } else {
        A = A0;
        Bt = Bt0;
    }
    f32x4 acc[4][4] = {};
    const int kswz = (l16 >> 1) & 3;

    for (int k0 = 0; k0 < DIM; k0 += 32) {
        __syncthreads();
#pragma unroll
        for (int i = 0; i < 2; i++) {
            int linear = i * 256 + tid;
            int m = linear >> 2, kgp = linear & 3;
            int kgl = kgp ^ ((m >> 1) & 3);
            async_cp16(A + (size_t)(m0 + m) * DIM + k0 + kgl * 8, As + linear * 8);
            async_cp16(Bt + (size_t)(n0 + m) * DIM + k0 + kgl * 8, Bs + linear * 8);
        }
        __syncthreads();
        bf16x8 af[4], bfr[4];
#pragma unroll
        for (int t = 0; t < 4; t++) {
            int ma = wm * 64 + t * 16 + l16;
            af[t] = *(const bf16x8*)(As + ma * 32 + ((quad ^ kswz) * 8));
            int nb = wn * 64 + t * 16 + l16;
            bfr[t] = *(const bf16x8*)(Bs + nb * 32 + ((quad ^ kswz) * 8));
        }
#pragma unroll
        for (int mt = 0; mt < 4; mt++)
#pragma unroll
            for (int nt = 0; nt < 4; nt++)
                acc[mt][nt] =
                    __builtin_amdgcn_mfma_f32_16x16x32_bf16(af[mt], bfr[nt], acc[mt][nt], 0, 0, 0);
    }

    if constexpr (MODE == 0) {
        const int h = (n0 + wn * 64) >> 6;  // this wave's head
        if (z <= 1) {
            const float* gvec = (z == 0) ? gq : gk;
            float* gate = (z == 0) ? gq_t : gk_t;
            unsigned short* O = (z == 0) ? Oq : Ok;
            float gv[4];
#pragma unroll
            for (int nt = 0; nt < 4; nt++) gv[nt] = gvec[nt * 16 + l16];
#pragma unroll
            for (int mt = 0; mt < 4; mt++) {
#pragma unroll
                for (int r = 0; r < 4; r++) {
                    float ss = 0.f;
#pragma unroll
                    for (int nt = 0; nt < 4; nt++) ss += acc[mt][nt][r] * acc[mt][nt][r];
#pragma unroll
                    for (int msk = 1; msk < 16; msk <<= 1) ss += __shfl_xor(ss, msk);
                    float rn = __builtin_amdgcn_rcpf(fmaxf(sqrtf(ss), 1e-12f));
                    float vn[4], gg = 0.f;
#pragma unroll
                    for (int nt = 0; nt < 4; nt++) {
                        vn[nt] = acc[mt][nt][r] * rn;
                        gg += vn[nt] * gv[nt];
                    }
#pragma unroll
                    for (int msk = 1; msk < 16; msk <<= 1) gg += __shfl_xor(gg, msk);
                    int tok = m0 + wm * 64 + mt * 16 + quad * 4 + r;
                    int b = tok >> 11, t = tok & 2047;
                    size_t rowbase = ((size_t)(b * HEADS + h) * T_SEQ + t) * HD;
#pragma unroll
                    for (int nt = 0; nt < 4; nt++) O[rowbase + nt * 16 + l16] = f2b(vn[nt]);
                    if (l16 == 0) gate[(b * HEADS + h) * T_SEQ + t] = gg;
                }
            }
        } else {
#pragma unroll
            for (int mt = 0; mt < 4; mt++) {
#pragma unroll
                for (int r = 0; r < 4; r++) {
                    int tok = m0 + wm * 64 + mt * 16 + quad * 4 + r;
                    int b = tok >> 11, t = tok & 2047;
                    size_t rowbase = ((size_t)(b * HEADS + h) * T_SEQ + t) * HD;
#pragma unroll
                    for (int nt = 0; nt < 4; nt++)
                        Ov[rowbase + nt * 16 + l16] = f2b(acc[mt][nt][r]);
                }
            }
        }
    } else {
        float bias_r[4];
#pragma unroll
        for (int nt = 0; nt < 4; nt++) bias_r[nt] = bias[n0 + wn * 64 + nt * 16 + l16];
#pragma unroll
        for (int mt = 0; mt < 4; mt++) {
#pragma unroll
            for (int r = 0; r < 4; r++) {
                int tok = m0 + wm * 64 + mt * 16 + quad * 4 + r;
#pragma unroll
                for (int nt = 0; nt < 4; nt++) {
                    int n = n0 + wn * 64 + nt * 16 + l16;
                    Oout[(size_t)tok * DIM + n] = acc[mt][nt][r] + bias_r[nt];
                }
            }
        }
    }
}

// ---------------------------------------------------------------------------
// Kernel 4: bf16 transpose V[bh][t][d] -> Vt[bh][d][t], fused gate_k scale.
// ---------------------------------------------------------------------------
__global__ __launch_bounds__(256) void vtrans_kernel(const unsigned short* __restrict__ Vn,
                                                     const float* __restrict__ gk_t,
                                                     unsigned short* __restrict__ Vt) {
    __shared__ float tile[64][65];
    const int bh = blockIdx.y;
    const int t0 = blockIdx.x * 64;
    const int r = threadIdx.x >> 3;
    const int c = (threadIdx.x & 7) * 8;
    const unsigned short* src = Vn + (size_t)bh * T_SEQ * HD;
#pragma unroll
    for (int half = 0; half < 2; half++) {
        int rr = r + half * 32;
        float gkv = gk_t[bh * T_SEQ + t0 + rr];
        bf16x8 v = *(const bf16x8*)(src + (size_t)(t0 + rr) * HD + c);
#pragma unroll
        for (int j = 0; j < 8; j++) tile[rr][c + j] = b2f((unsigned short)v[j]) * gkv;
    }
    __syncthreads();
    unsigned short* dst = Vt + (size_t)bh * HD * T_SEQ;
#pragma unroll
    for (int half = 0; half < 2; half++) {
        int dd = r + half * 32;
        bf16x8 o;
#pragma unroll
        for (int j = 0; j < 8; j++) o[j] = (short)f2b(tile[c + j][dd]);
        *(bf16x8*)(dst + (size_t)dd * T_SEQ + t0 + c) = o;
    }
}

// ---------------------------------------------------------------------------
// Kernel 5: MFMA gated attention (R8 LDS structure) + s-split across blocks.
// blockIdx.z = b*2 + s_half; each block does T_SEQ/2 of the s range and
// writes a bf16 partial (gq applied; sum over s is linear, split is exact).
// Grid 2048 blocks -> ~5 blocks/CU (LDS 32KB) vs 2 before.
// ---------------------------------------------------------------------------
__global__ __launch_bounds__(256) void attn_mfma_kernel(
    const unsigned short* __restrict__ Qn, const unsigned short* __restrict__ Kn,
    const unsigned short* __restrict__ Vt, const float* __restrict__ gateq,
    unsigned short* __restrict__ collp0, unsigned short* __restrict__ collp1) {
    __shared__ __align__(16) unsigned short Ks[2][64 * 64];   // [s][d], swizzled groups
    __shared__ __align__(16) unsigned short VtL[2][64 * 64];  // [d][s], swizzled groups
    const int tid = threadIdx.x;
    const int lane = tid & 63, w = tid >> 6;
    const int quad = lane >> 4, l16 = lane & 15;
    const int t0 = blockIdx.x * 128;
    const int h = blockIdx.y;
    const int zz = blockIdx.z;
    const int b = zz >> 1, shalf = zz & 1;
    const int sbase = shalf * (T_SEQ / 2);
    const int bh = b * HEADS + h;
    const size_t base = (size_t)bh * T_SEQ * HD;  // == bh*HD*T_SEQ for Vt
    constexpr float K1 = -SHARP * LOG2E;
    constexpr float K0 = THRESH * SHARP * LOG2E;

    // Detect v_permlane16_swap_b32 output order once (uniform).
    int det0 = quad, det1 = quad + 4;
    asm("v_permlane16_swap_b32 %0, %1" : "+v"(det0), "+v"(det1));
    const bool flagA = (__builtin_amdgcn_readfirstlane(det0) == 0);

    // Q (B-operand of QK) fragments: 32 rows/wave, 2 m-tiles, in regs.
    bf16x8 fq[2][2];
#pragma unroll
    for (int mt = 0; mt < 2; mt++) {
        const unsigned short* qrow = Qn + base + (size_t)(t0 + w * 32 + mt * 16 + l16) * HD;
        fq[mt][0] = *(const bf16x8*)(qrow + quad * 8);
        fq[mt][1] = *(const bf16x8*)(qrow + 32 + quad * 8);
    }

    f32x4 oacc[4][2] = {};  // [dt][mt], O^T C-layout
    const int srow = tid >> 3;     // staging row 0..31 (+32 second inst)
    const int sgp = tid & 7;       // physical 16B group
    const int swz = l16 & 7;

    auto stage_chunk = [&](unsigned short* ksn, unsigned short* vtn, int s0) {
#pragma unroll
        for (int half = 0; half < 2; half++) {
            int row = srow + half * 32;
            int g = sgp ^ (row & 7);  // logical group for this physical slot
            async_cp16(Kn + base + (size_t)(s0 + row) * HD + g * 8, ksn + row * 64 + sgp * 8);
            async_cp16(Vt + base + (size_t)row * T_SEQ + s0 + g * 8, vtn + row * 64 + sgp * 8);
        }
    };

    auto do_chunk = [&](const unsigned short* ksb, const unsigned short* vtb) {
        // ---- QK phase: S^T = K Q^T; sigmoid; bf16 S stays in registers ----
        unsigned int p[2][4][2];  // [mt][ct][dword]; lane: s=ct*16+quad*4+r, m=mt*16+l16
#pragma unroll
        for (int ct = 0; ct < 4; ct++) {
            const unsigned short* krow = ksb + (ct * 16 + l16) * 64;
            bf16x8 fk0 = *(const bf16x8*)(krow + (quad ^ swz) * 8);
            bf16x8 fk1 = *(const bf16x8*)(krow + ((quad + 4) ^ swz) * 8);
#pragma unroll
            for (int mt = 0; mt < 2; mt++) {
                f32x4 sacc = {0.f, 0.f, 0.f, 0.f};
                sacc = __builtin_amdgcn_mfma_f32_16x16x32_bf16(fk0, fq[mt][0], sacc, 0, 0, 0);
                sacc = __builtin_amdgcn_mfma_f32_16x16x32_bf16(fk1, fq[mt][1], sacc, 0, 0, 0);
                float w0 = __builtin_amdgcn_rcpf(1.f + __builtin_amdgcn_exp2f(fmaf(sacc[0], K1, K0)));
                float w1 = __builtin_amdgcn_rcpf(1.f + __builtin_amdgcn_exp2f(fmaf(sacc[1], K1, K0)));
                float w2 = __builtin_amdgcn_rcpf(1.f + __builtin_amdgcn_exp2f(fmaf(sacc[2], K1, K0)));
                float w3 = __builtin_amdgcn_rcpf(1.f + __builtin_amdgcn_exp2f(fmaf(sacc[3], K1, K0)));
                p[mt][ct][0] = pack2_bf16(w0, w1);
                p[mt][ct][1] = pack2_bf16(w2, w3);
            }
        }
        // ---- SV phase: O^T += V^T S^T, B-frag built via permlane16_swap ----
#pragma unroll
        for (int kh = 0; kh < 2; kh++) {
            int gv = (4 * kh + 2 * (quad & 1) + (quad >> 1)) ^ swz;
            bf16x8 fv[4];
#pragma unroll
            for (int dt = 0; dt < 4; dt++)
                fv[dt] = *(const bf16x8*)(vtb + (dt * 16 + l16) * 64 + gv * 8);
#pragma unroll
            for (int mt = 0; mt < 2; mt++) {
                unsigned int aL = p[mt][2 * kh][0], aH = p[mt][2 * kh][1];
                unsigned int bL = p[mt][2 * kh + 1][0], bH = p[mt][2 * kh + 1][1];
                asm("v_permlane16_swap_b32 %0, %1" : "+v"(aL), "+v"(bL));
                asm("v_permlane16_swap_b32 %0, %1" : "+v"(aH), "+v"(bH));
                u32x4 bt;
                if (flagA) {  // wave-uniform branch, no per-lane selects
                    bt.x = aL; bt.y = aH; bt.z = bL; bt.w = bH;
                } else {
                    bt.x = bL; bt.y = bH; bt.z = aL; bt.w = aH;
                }
                bf16x8 fs = __builtin_bit_cast(bf16x8, bt);
#pragma unroll
                for (int dt = 0; dt < 4; dt++)
                    oacc[dt][mt] =
                        __builtin_amdgcn_mfma_f32_16x16x32_bf16(fv[dt], fs, oacc[dt][mt], 0, 0, 0);
            }
        }
        __syncthreads();
    };

    stage_chunk(&Ks[0][0], &VtL[0][0], sbase);
    __syncthreads();

    for (int j = 0; j < T_SEQ / 256; j++) {
        // even chunk (buf 0): prefetch odd chunk into buf 1 (always in range)
        stage_chunk(&Ks[1][0], &VtL[1][0], sbase + j * 128 + 64);
        do_chunk(&Ks[0][0], &VtL[0][0]);
        // odd chunk (buf 1): prefetch next even chunk into buf 0
        if (j + 1 < T_SEQ / 256) stage_chunk(&Ks[0][0], &VtL[0][0], sbase + j * 128 + 128);
        do_chunk(&Ks[1][0], &VtL[1][0]);
    }

    // ---- epilogue: O^T lanes hold 4 consecutive d; * gate_q, b64 writes ----
    unsigned short* collp = shalf ? collp1 : collp0;
#pragma unroll
    for (int mt = 0; mt < 2; mt++) {
        int t = t0 + w * 32 + mt * 16 + l16;
        float gq_v = gateq[bh * T_SEQ + t];
        unsigned short* dst = collp + ((size_t)b * T_SEQ + t) * DIM + h * HD;
#pragma unroll
        for (int dt = 0; dt < 4; dt++) {
            ushort4 o;
            o.x = f2b(oacc[dt][mt][0] * gq_v);
            o.y = f2b(oacc[dt][mt][1] * gq_v);
            o.z = f2b(oacc[dt][mt][2] * gq_v);
            o.w = f2b(oacc[dt][mt][3] * gq_v);
            *(ushort4*)(dst + dt * 16 + quad * 4) = o;
        }
    }
}

// ---------------------------------------------------------------------------
// Kernel 6: merge s-half partials: p0 <- bf16(p0 + p1). Memory-bound ~25MB.
// ---------------------------------------------------------------------------
__global__ __launch_bounds__(256) void merge_kernel(unsigned short* __restrict__ p0,
                                                    const unsigned short* __restrict__ p1) {
    size_t i = ((size_t)blockIdx.x * 256 + threadIdx.x) * 8;
    bf16x8 a = *(const bf16x8*)(p0 + i);
    bf16x8 c = *(const bf16x8*)(p1 + i);
    bf16x8 o;
#pragma unroll
    for (int j = 0; j < 8; j++)
        o[j] = (short)f2b(b2f((unsigned short)a[j]) + b2f((unsigned short)c[j]));
    *(bf16x8*)(p0 + i) = o;
}

// ---------------------------------------------------------------------------
extern "C" void kernel_launch(void* const* d_in, const int* in_sizes, int n_in,
                              void* d_out, int out_size, void* d_ws, size_t ws_size,
                              hipStream_t stream) {
    const float* x = (const float*)d_in[0];
    const float* Wq = (const float*)d_in[1];
    const float* Wk = (const float*)d_in[2];
    const float* Wv = (const float*)d_in[3];
    const float* gq = (const float*)d_in[4];
    const float* gk = (const float*)d_in[5];
    const float* Wo = (const float*)d_in[6];
    const float* bo = (const float*)d_in[7];
    const float* lnw = (const float*)d_in[8];
    const float* lnb = (const float*)d_in[9];
    float* out = (float*)d_out;

    // Workspace ~59.3 MB (R2 used 59.3 MB successfully). Aliases safe by
    // stream ordering: Vt overwrites xnb (dead after QKV GEMM); collb0
    // overwrites xb (dead after QKV GEMM).
    unsigned short* ws = (unsigned short*)d_ws;
    unsigned short* xnb = ws;                           // bf16 [4096][1024]
    unsigned short* xb = xnb + (size_t)NTOK * DIM;      // bf16 [4096][1024]
    unsigned short* Wqt = xb + (size_t)NTOK * DIM;      // bf16 [1024][1024] (W^T)
    unsigned short* Wkt = Wqt + (size_t)DIM * DIM;
    unsigned short* Wvt = Wkt + (size_t)DIM * DIM;
    unsigned short* Wot = Wvt + (size_t)DIM * DIM;
    unsigned short* Q16 = Wot + (size_t)DIM * DIM;      // bf16 [B,H,T,hd] (normalized)
    unsigned short* K16 = Q16 + (size_t)NTOK * DIM;     // bf16 (normalized)
    unsigned short* Vn = K16 + (size_t)NTOK * DIM;      // bf16 [B,H,T,hd]
    float* gq_t = (float*)(Vn + (size_t)NTOK * DIM);    // [B,H,T]
    float* gk_t = gq_t + NBATCH * HEADS * T_SEQ;
    unsigned short* collb1 = (unsigned short*)(gk_t + NBATCH * HEADS * T_SEQ);  // bf16 partial 1
    unsigned short* Vt = xnb;     // alias: bf16 [B,H,hd,T], gk-scaled
    unsigned short* collb0 = xb;  // alias: bf16 partial 0 / merged collapse

    ln_xnorm_kernel<<<NTOK / 4, 256, 0, stream>>>(x, lnw, lnb, xnb, xb);
    wtrans_kernel<<<dim3(16, 16, 4), 256, 0, stream>>>(Wq, Wk, Wv, Wo, Wqt, Wkt, Wvt, Wot);
    gemm_mfma_kernel<0><<<dim3(NTOK / 128, DIM / 128, 3), 256, 0, stream>>>(
        xnb, xb, Wqt, Wkt, Wvt, nullptr, gq, gk, Q16, K16, Vn, gq_t, gk_t, nullptr);
    vtrans_kernel<<<dim3(T_SEQ / 64, NBATCH * HEADS), 256, 0, stream>>>(Vn, gk_t, Vt);
    attn_mfma_kernel<<<dim3(T_SEQ / 128, HEADS, NBATCH * 2), 256, 0, stream>>>(
        Q16, K16, Vt, gq_t, collb0, collb1);
    merge_kernel<<<(NTOK * DIM) / (256 * 8), 256, 0, stream>>>(collb0, collb1);
    gemm_mfma_kernel<1><<<dim3(NTOK / 128, DIM / 128, 1), 256, 0, stream>>>(
        collb0, nullptr, Wot, nullptr, nullptr, bo, nullptr, nullptr, nullptr, nullptr, nullptr,
        nullptr, nullptr, out);
}